// Round 2
// 640.866 us; speedup vs baseline: 1.3509x; 1.3509x over previous
//
#include <hip/hip_runtime.h>
#include <cmath>

#define B 8
#define DIM 1024
#define T 2048
#define K 8
#define CS 512
#define CHUNK 128
#define TT 128             // t-columns per block
#define TPL 2              // t-columns per lane
#define NW 8               // waves per block (512 threads)
#define OPW 64             // o's per wave (8 waves x 64 = CS)
#define OG 8               // o's per register-tile group (32 W dwords/iter -> one batched wait)
#define NG (OPW / OG)      // 8 groups per wave
#define EPS 1e-10f

// Block = (b,k) x 128-wide t-tile, 8 waves. X tile staged in LDS (float2/lane
// -> ds_read_b64); W via wave-uniform scalar loads, only 8x s_load_dwordx4 per
// inner iteration so the compiler can batch them into one lgkmcnt wait; each
// lane owns TWO t-columns so every W dword feeds 2 FMAs instead of 1.
// LDS (72 KB) is the occupancy limiter: 2 blocks/CU = 4 waves/SIMD.
__global__ __launch_bounds__(512, 2) void gumbel_fused_kernel(
    const float* __restrict__ x,          // [B, K, CHUNK, T]
    const float* __restrict__ proj_w,     // [K, CS, CHUNK]
    const float* __restrict__ proj_b,     // [K, CS]
    const float* __restrict__ codebooks,  // [K, CS, CHUNK]
    const float* __restrict__ noise,      // [B, K, CS, T]
    float* __restrict__ out,              // [B, K, CHUNK, T] then K perplexities
    unsigned int* __restrict__ counts)    // [K, CS]
{
    __shared__ float Xs[CHUNK * TT];      // 64 KB
    __shared__ float redv[NW][TT];        // 4 KB
    __shared__ int   redi[NW][TT];        // 4 KB

    const int tid = threadIdx.x;
    const int nt = T / TT;                // 16
    const int t0 = (blockIdx.x % nt) * TT;
    const int bk = blockIdx.x / nt;       // b*K + k
    const int k = bk % K;

    // ---- stage X tile [CHUNK][TT] into LDS (coalesced float4) ----
    {
        const float* xb = x + (size_t)bk * CHUNK * T + t0;
        const int nv = CHUNK * TT / 4;    // 4096 float4
        for (int i = tid; i < nv; i += 512) {
            const int row = i >> 5;       // TT/4 = 32 float4 per row
            const int c4 = (i & 31) << 2;
            *(float4*)(&Xs[row * TT + c4]) = *(const float4*)(xb + (size_t)row * T + c4);
        }
    }
    __syncthreads();

    // wave index forced wave-uniform -> scalar W addressing
    const int w = __builtin_amdgcn_readfirstlane(tid >> 6);
    const int lane = tid & 63;
    const int tl = lane * TPL;            // this lane's 2 t-columns: tl, tl+1

    const float* wb = proj_w + ((size_t)k * CS + w * OPW) * CHUNK;
    const float* bb = proj_b + (size_t)k * CS + w * OPW;
    const float* nb = noise + ((size_t)bk * CS + w * OPW) * T + t0 + tl;

    float bv0 = -INFINITY, bv1 = -INFINITY;
    int bi0 = 0, bi1 = 0;

    for (int og = 0; og < NG; ++og) {
        float acc[OG][TPL];
#pragma unroll
        for (int oo = 0; oo < OG; ++oo) { acc[oo][0] = 0.f; acc[oo][1] = 0.f; }

        const float* wrow = wb + (size_t)(og * OG) * CHUNK;
        for (int cb = 0; cb < CHUNK; cb += 4) {
            float2 xv[4];
#pragma unroll
            for (int j = 0; j < 4; ++j)
                xv[j] = *(const float2*)(&Xs[(cb + j) * TT + tl]);
#pragma unroll
            for (int oo = 0; oo < OG; ++oo) {
                const float* wr = wrow + oo * CHUNK + cb;  // wave-uniform, imm offsets
#pragma unroll
                for (int j = 0; j < 4; ++j) {
                    acc[oo][0] = fmaf(wr[j], xv[j].x, acc[oo][0]);
                    acc[oo][1] = fmaf(wr[j], xv[j].y, acc[oo][1]);
                }
            }
        }

        // epilogue: bias + gumbel, running argmax (ascending o, strict >)
#pragma unroll
        for (int oo = 0; oo < OG; ++oo) {
            const int o = og * OG + oo;
            const float bias = bb[o];
            const float2 u = *(const float2*)(nb + (size_t)o * T);
            const float g0 = -logf(-logf(u.x + EPS) + EPS);
            const float g1 = -logf(-logf(u.y + EPS) + EPS);
            const float l0 = acc[oo][0] + bias + g0;
            const float l1 = acc[oo][1] + bias + g1;
            const int oi = w * OPW + o;
            if (l0 > bv0) { bv0 = l0; bi0 = oi; }
            if (l1 > bv1) { bv1 = l1; bi1 = oi; }
        }
    }

    redv[w][tl] = bv0; redv[w][tl + 1] = bv1;
    redi[w][tl] = bi0; redi[w][tl + 1] = bi1;
    __syncthreads();

    // cross-wave argmax; ascending wave order keeps lowest-o on ties
    if (tid < TT) {
        float best = redv[0][tid];
        int besti = redi[0][tid];
#pragma unroll
        for (int ww = 1; ww < NW; ++ww) {
            if (redv[ww][tid] > best) { best = redv[ww][tid]; besti = redi[ww][tid]; }
        }
        redi[0][tid] = besti;
        atomicAdd(&counts[k * CS + besti], 1u);
    }
    __syncthreads();

    // ---- scatter codebook rows to output tile (stores coalesced in t) ----
    {
        const int t = tid & (TT - 1);
        const int cq = tid >> 7;          // 4 groups of 32 c's
        const int row = redi[0][t];
        const float* crow = codebooks + ((size_t)k * CS + row) * CHUNK + cq * 32;
        float* ob = out + (size_t)bk * CHUNK * T + t0 + t;
#pragma unroll
        for (int i = 0; i < 8; ++i) {
            const float4 v = *(const float4*)(crow + i * 4);
            const int c = cq * 32 + i * 4;
            ob[(size_t)(c + 0) * T] = v.x;
            ob[(size_t)(c + 1) * T] = v.y;
            ob[(size_t)(c + 2) * T] = v.z;
            ob[(size_t)(c + 3) * T] = v.w;
        }
    }
}

// Perplexity per codebook from the histogram. Wave k handles codebook k.
__global__ void perplexity_kernel(const unsigned int* __restrict__ counts,
                                  float* __restrict__ out)
{
    const int k = threadIdx.x >> 6;
    const int lane = threadIdx.x & 63;
    float sum = 0.0f;
    const float inv_bt = 1.0f / (float)(B * T);
#pragma unroll
    for (int i = lane; i < CS; i += 64) {
        const float avg = (float)counts[k * CS + i] * inv_bt;
        sum += -avg * logf(avg + 1e-8f);   // avg==0 contributes exact 0
    }
#pragma unroll
    for (int off = 32; off > 0; off >>= 1) sum += __shfl_down(sum, off, 64);
    if (lane == 0) out[(size_t)B * DIM * T + k] = expf(sum);
}

extern "C" void kernel_launch(void* const* d_in, const int* in_sizes, int n_in,
                              void* d_out, int out_size, void* d_ws, size_t ws_size,
                              hipStream_t stream) {
    const float* x         = (const float*)d_in[0];
    const float* proj_w    = (const float*)d_in[1];
    const float* proj_b    = (const float*)d_in[2];
    const float* codebooks = (const float*)d_in[3];
    const float* noise     = (const float*)d_in[4];
    float* out             = (float*)d_out;
    unsigned int* counts   = (unsigned int*)d_ws;

    // d_ws is re-poisoned before every timed launch -> zero the histogram
    hipMemsetAsync(counts, 0, (size_t)K * CS * sizeof(unsigned int), stream);

    const int nblocks = B * K * (T / TT);   // 1024 = exactly 2 blocks/CU, one round
    gumbel_fused_kernel<<<nblocks, 512, 0, stream>>>(
        x, proj_w, proj_b, codebooks, noise, out, counts);

    perplexity_kernel<<<1, 512, 0, stream>>>(counts, out);
}